// Round 6
// baseline (579.475 us; speedup 1.0000x reference)
//
#include <hip/hip_runtime.h>

// CrossAttentionPro on MI355X — Round 5:
//  + flash_chained split over s (flash-decoding): grid 512 -> 1024 blocks
//    (4/CU, was grid-limited at 2/CU = the R4 360us miss). Each half writes
//    unnormalized partial O (f32) + (m,l); combine_k merges into CV2.
//  Inner K-loop / softmax / PV identical to R4 (proven correct).
// All matmuls NT; v stored transposed; catt_y2x computed transposed.

typedef _Float16 half_t;
typedef _Float16 half8 __attribute__((ext_vector_type(8)));
typedef _Float16 half4v __attribute__((ext_vector_type(4)));
typedef float floatx4 __attribute__((ext_vector_type(4)));

constexpr int Bc = 2, Tc = 2048, Mc = 1024, Cc = 512, Hc = 8, Dc = 64;
constexpr long BTC = (long)Bc * Tc * Cc;

enum { EPI_F16STORE = 0, EPI_QKV = 1, EPI_CVALDIFF = 2, EPI_PROJ = 3 };

struct EpiParams {
  half_t* h0;        // primary f16 dest
  half_t* h1;        // k (QKV) / CV2 source (CVALDIFF)
  half_t* h2;        // v^T (QKV)
  float* f0;         // final fp32 out (PROJ)
  const float* bias;
  float scale;
  int ldc;
  long bstride;
  int seq;
};

// async global->LDS, 16B per lane; dst must be wave-uniform base + lane*16.
__device__ __forceinline__ void gld_lds16(const half_t* g, half_t* l) {
  __builtin_amdgcn_global_load_lds(
      (const __attribute__((address_space(1))) void*)g,
      (__attribute__((address_space(3))) void*)l, 16, 0, 0);
}

// ---------------------------------------------------------------- GEMM (NT)
// R2-proven kernel: C[r,c] = sum_k A[r,k]*Bt[c,k], BK=32 swizzled async
// staging (measured 0 bank conflicts), direct per-element epilogue.
template <int BM, int BN, int WMG, int WNG, int EPI>
__global__ __launch_bounds__(256) void gemm_nt(
    const half_t* __restrict__ A, const half_t* __restrict__ Bt,
    int K, int lda, int ldb, long bsA, long bsB, EpiParams ep)
{
  constexpr int BK = 32;
  constexpr int WTM = BM / WMG, WTN = BN / WNG;
  constexpr int MI = WTM / 16, NI = WTN / 16;
  constexpr int ACHUNKS = BM * 4;
  constexpr int BCHUNKS = BN * 4;
  __shared__ __align__(16) half_t As[BM * BK];
  __shared__ __align__(16) half_t Bs[BN * BK];

  const int tid = threadIdx.x;
  const int lane = tid & 63;
  const int wave = tid >> 6;
  const int wm = wave / WNG, wn = wave % WNG;
  const int r16 = lane & 15, g = lane >> 4;
  const int z = blockIdx.z;
  const long m0 = (long)blockIdx.y * BM;
  const long n0 = (long)blockIdx.x * BN;
  const half_t* Abase = A + (long)z * bsA + m0 * (long)lda;
  const half_t* Bbase = Bt + (long)z * bsB + n0 * (long)ldb;

  const int rA = wm * WTM + r16;
  const int rB = wn * WTN + r16;
  const int swA = (g ^ ((rA >> 1) & 3)) * 8;
  const int swB = (g ^ ((rB >> 1) & 3)) * 8;

  floatx4 acc[MI][NI];
#pragma unroll
  for (int mi = 0; mi < MI; ++mi)
#pragma unroll
    for (int ni = 0; ni < NI; ++ni)
      acc[mi][ni] = floatx4{0.f, 0.f, 0.f, 0.f};

  for (int kt = 0; kt < K; kt += BK) {
#pragma unroll
    for (int i = 0; i < (ACHUNKS + 255) / 256; ++i) {
      const int c = tid + i * 256;
      if (ACHUNKS % 256 == 0 || c < ACHUNKS) {
        const int row = c >> 2, js = c & 3;
        const int jg = js ^ ((row >> 1) & 3);
        gld_lds16(Abase + (long)row * lda + kt + jg * 8, As + c * 8);
      }
    }
#pragma unroll
    for (int i = 0; i < (BCHUNKS + 255) / 256; ++i) {
      const int c = tid + i * 256;
      if (BCHUNKS % 256 == 0 || c < BCHUNKS) {
        const int row = c >> 2, js = c & 3;
        const int jg = js ^ ((row >> 1) & 3);
        gld_lds16(Bbase + (long)row * ldb + kt + jg * 8, Bs + c * 8);
      }
    }
    __syncthreads();
    half8 aF[MI], bF[NI];
#pragma unroll
    for (int mi = 0; mi < MI; ++mi)
      aF[mi] = *reinterpret_cast<const half8*>(&As[(rA + mi * 16) * BK + swA]);
#pragma unroll
    for (int ni = 0; ni < NI; ++ni)
      bF[ni] = *reinterpret_cast<const half8*>(&Bs[(rB + ni * 16) * BK + swB]);
#pragma unroll
    for (int mi = 0; mi < MI; ++mi)
#pragma unroll
      for (int ni = 0; ni < NI; ++ni)
        acc[mi][ni] = __builtin_amdgcn_mfma_f32_16x16x32_f16(aF[mi], bF[ni], acc[mi][ni], 0, 0, 0);
    __syncthreads();
  }

  // epilogue: C/D layout col=lane&15, row=(lane>>4)*4+reg  [m89-verified]
#pragma unroll
  for (int mi = 0; mi < MI; ++mi) {
#pragma unroll
    for (int ni = 0; ni < NI; ++ni) {
#pragma unroll
      for (int reg = 0; reg < 4; ++reg) {
        const int r = (int)m0 + wm * WTM + mi * 16 + g * 4 + reg;
        const int c = (int)n0 + wn * WTN + ni * 16 + r16;
        const float v = acc[mi][ni][reg];
        if constexpr (EPI == EPI_F16STORE) {
          ep.h0[(long)z * ep.bstride + (long)r * ep.ldc + c] = (half_t)(v * ep.scale);
        } else if constexpr (EPI == EPI_QKV) {
          const float val = v + ep.bias[c];
          const int which = c >> 9;     // 0=q 1=k 2=v
          const int cc2 = c & 511;
          const int h = cc2 >> 6, d = cc2 & 63;
          const int b = r / ep.seq, t = r - b * ep.seq;
          const long bh = (long)(b * Hc + h);
          if (which == 0)      ep.h0[(bh * ep.seq + t) * Dc + d] = (half_t)(val * 0.125f);
          else if (which == 1) ep.h1[(bh * ep.seq + t) * Dc + d] = (half_t)val;
          else                 ep.h2[(bh * Dc + d) * ep.seq + t] = (half_t)val;
        } else if constexpr (EPI == EPI_CVALDIFF) {
          const int b = z >> 3, h = z & 7;
          const long idx = ((long)(b * Tc + r)) * Cc + h * Dc + c;
          ep.h0[idx] = (half_t)(v - (float)ep.h1[idx]); // diff = cval_x2y - cval_y2x
        } else {  // EPI_PROJ
          ep.f0[(long)r * Cc + c] = v + ep.bias[c];
        }
      }
    }
  }
}

// --------------------------------------------- flash chained attention
// Per block: 64 q-rows of one z, HALF the s-range (blockIdx.z selects
// s in [half*1024, half*1024+1024)), s-tiles of 128. Writes unnormalized
// partial O (f32) to PO[half] and per-row (m,l) to ML. combine_k merges.
__global__ __launch_bounds__(256, 4) void flash_chained(
    const half_t* __restrict__ CATT, const half_t* __restrict__ CATTT,
    const half_t* __restrict__ VXT, const int* __restrict__ mask,
    float* __restrict__ PO, float2* __restrict__ ML)
{
  constexpr int QT = 64, ST = 128, BK = 32;
  // uni: union{ As[64*32]=2048 + Bs[128*32]=4096 halfs | P 4 waves*16*136 }
  __shared__ __align__(16) half_t uni[8704];
  __shared__ __align__(16) half_t Vb[8192];   // 4 sub-tiles [64][32]
  half_t* As = uni;
  half_t* Bs = uni + 2048;

  const int tid = threadIdx.x, lane = tid & 63, w = tid >> 6;
  const int r16 = lane & 15, g = lane >> 4;
  const int z = blockIdx.y, q0 = blockIdx.x * QT;
  const int half = blockIdx.z;
  const int sbeg = half * 1024, send = sbeg + 1024;
  const int b = z >> 3, h = z & 7;
  const half_t* Ab = CATT + ((long)z * Tc + q0) * Mc;
  const half_t* Bb = CATTT + (long)z * Tc * Mc;
  const half_t* Vbase = VXT + (long)z * Dc * Tc;

  const int sw = (g ^ ((r16 >> 1) & 3)) * 8;

  floatx4 oacc[4];
#pragma unroll
  for (int no = 0; no < 4; ++no) oacc[no] = floatx4{0.f, 0.f, 0.f, 0.f};
  float mrun[4], lrun[4];
#pragma unroll
  for (int reg = 0; reg < 4; ++reg) { mrun[reg] = -1e30f; lrun[reg] = 0.f; }

  for (int s0 = sbeg; s0 < send; s0 += ST) {
    // stage V: 4 sub-tiles [64 d][32 s], R2 swizzle inside each
#pragma unroll
    for (int i = 0; i < 4; ++i) {
      const int c = tid + i * 256;
      const int sub = c >> 8, cc = c & 255;
      const int d = cc >> 2, js = cc & 3;
      const int jg = js ^ ((d >> 1) & 3);
      gld_lds16(Vbase + (long)d * Tc + s0 + sub * 32 + jg * 8, Vb + c * 8);
    }
    floatx4 sacc[8];
#pragma unroll
    for (int ni = 0; ni < 8; ++ni) sacc[ni] = floatx4{0.f, 0.f, 0.f, 0.f};

    for (int kt = 0; kt < Mc; kt += BK) {
      {  // As: 64 rows x 4 chunks = 256 -> 1/thread
        const int row = tid >> 2, js = tid & 3;
        const int jg = js ^ ((row >> 1) & 3);
        gld_lds16(Ab + (long)row * Mc + kt + jg * 8, As + tid * 8);
      }
#pragma unroll
      for (int i = 0; i < 2; ++i) {  // Bs: 128 x 4 = 512 -> 2/thread
        const int c = tid + i * 256;
        const int row = c >> 2, js = c & 3;
        const int jg = js ^ ((row >> 1) & 3);
        gld_lds16(Bb + ((long)(s0 + row)) * Mc + kt + jg * 8, Bs + c * 8);
      }
      __syncthreads();
      const half8 aF = *reinterpret_cast<const half8*>(&As[(w * 16 + r16) * BK + sw]);
#pragma unroll
      for (int ni = 0; ni < 8; ++ni) {
        const half8 bF = *reinterpret_cast<const half8*>(&Bs[(ni * 16 + r16) * BK + sw]);
        sacc[ni] = __builtin_amdgcn_mfma_f32_16x16x32_f16(aF, bF, sacc[ni], 0, 0, 0);
      }
      __syncthreads();
    }

    // ---- masked online softmax on sacc (C-layout) ----
    float sv[8][4];
#pragma unroll
    for (int ni = 0; ni < 8; ++ni)
#pragma unroll
      for (int reg = 0; reg < 4; ++reg) sv[ni][reg] = sacc[ni][reg] * 0.125f;
#pragma unroll
    for (int reg = 0; reg < 4; ++reg) {
      const long trow = (long)(q0 + w * 16 + g * 4 + reg) * Tc + s0;
#pragma unroll
      for (int ni = 0; ni < 8; ++ni)
        if (mask[trow + ni * 16 + r16] == 0) sv[ni][reg] = -__builtin_inff();
    }
#pragma unroll
    for (int reg = 0; reg < 4; ++reg) {
      float tm = sv[0][reg];
#pragma unroll
      for (int ni = 1; ni < 8; ++ni) tm = fmaxf(tm, sv[ni][reg]);
      tm = fmaxf(tm, __shfl_xor(tm, 1));
      tm = fmaxf(tm, __shfl_xor(tm, 2));
      tm = fmaxf(tm, __shfl_xor(tm, 4));
      tm = fmaxf(tm, __shfl_xor(tm, 8));
      const float mnew = fmaxf(mrun[reg], tm);
      const float alpha = __expf(mrun[reg] - mnew);
      mrun[reg] = mnew;
      float ps = 0.f;
#pragma unroll
      for (int ni = 0; ni < 8; ++ni) {
        const float e = __expf(sv[ni][reg] - mnew);
        ps += e;
        uni[w * 2176 + (g * 4 + reg) * 136 + ni * 16 + r16] = (half_t)e;
      }
      ps += __shfl_xor(ps, 1);
      ps += __shfl_xor(ps, 2);
      ps += __shfl_xor(ps, 4);
      ps += __shfl_xor(ps, 8);
      lrun[reg] = lrun[reg] * alpha + ps;
#pragma unroll
      for (int no = 0; no < 4; ++no) oacc[no][reg] *= alpha;
    }

    // ---- PV: O[t,d] += P[t,s]·VXT[d,s] ----
#pragma unroll
    for (int ks2 = 0; ks2 < 4; ++ks2) {
      const half8 aP = *reinterpret_cast<const half8*>(
          &uni[w * 2176 + r16 * 136 + ks2 * 32 + g * 8]);
#pragma unroll
      for (int no = 0; no < 4; ++no) {
        const half8 bV = *reinterpret_cast<const half8*>(
            &Vb[ks2 * 2048 + (no * 16 + r16) * BK + sw]);
        oacc[no] = __builtin_amdgcn_mfma_f32_16x16x32_f16(aP, bV, oacc[no], 0, 0, 0);
      }
    }
    __syncthreads();
  }

  // epilogue: unnormalized O -> PO[half], stats -> ML
  float* POh = PO + (long)half * BTC;
#pragma unroll
  for (int reg = 0; reg < 4; ++reg) {
    const int t = q0 + w * 16 + g * 4 + reg;
    if (r16 == 0) ML[((long)(z * 2 + half)) * Tc + t] = float2{mrun[reg], lrun[reg]};
#pragma unroll
    for (int no = 0; no < 4; ++no) {
      const int d = no * 16 + r16;
      POh[((long)(b * Tc + t)) * Cc + h * 64 + d] = oacc[no][reg];
    }
  }
}

// ------------------------------------------------- combine the two s-halves
__global__ __launch_bounds__(256) void combine_k(
    const float* __restrict__ PO, const float2* __restrict__ ML,
    half_t* __restrict__ CV2)
{
  const long idx = (long)blockIdx.x * 256 + threadIdx.x;   // over BTC/4
  const long c4 = idx * 4;
  const int c = (int)(c4 & (Cc - 1));
  const long bt = c4 >> 9;                 // b*Tc + t
  const int h = c >> 6;
  const int b = (int)(bt >> 11), t = (int)(bt & (Tc - 1));
  const int z = b * Hc + h;
  const float2 ml0 = ML[((long)(z * 2 + 0)) * Tc + t];
  const float2 ml1 = ML[((long)(z * 2 + 1)) * Tc + t];
  const float mm = fmaxf(ml0.x, ml1.x);
  const float w0 = __expf(ml0.x - mm), w1 = __expf(ml1.x - mm);
  const float inv = 1.f / (w0 * ml0.y + w1 * ml1.y);
  const float4 o0 = reinterpret_cast<const float4*>(PO)[idx];
  const float4 o1 = reinterpret_cast<const float4*>(PO + BTC)[idx];
  half4v r;
  r[0] = (half_t)((o0.x * w0 + o1.x * w1) * inv);
  r[1] = (half_t)((o0.y * w0 + o1.y * w1) * inv);
  r[2] = (half_t)((o0.z * w0 + o1.z * w1) * inv);
  r[3] = (half_t)((o0.w * w0 + o1.w * w1) * inv);
  reinterpret_cast<half4v*>(CV2)[idx] = r;
}

// ------------------------------------------------------------- row softmax
__device__ inline float wave_red_max(float v) {
#pragma unroll
  for (int o = 32; o > 0; o >>= 1) v = fmaxf(v, __shfl_xor(v, o));
  return v;
}
__device__ inline float wave_red_sum(float v) {
#pragma unroll
  for (int o = 32; o > 0; o >>= 1) v += __shfl_xor(v, o);
  return v;
}

template <int NC>
__global__ __launch_bounds__(256) void softmax_rows(half_t* __restrict__ buf)
{
  constexpr int VEC = NC / 256;
  typedef _Float16 hvec __attribute__((ext_vector_type(VEC)));
  const long row = blockIdx.x;
  const int tid = threadIdx.x, lane = tid & 63, wave = tid >> 6;
  half_t* p = buf + row * NC + tid * VEC;
  __shared__ float red[4];

  float v[VEC];
  hvec hv = *reinterpret_cast<const hvec*>(p);
#pragma unroll
  for (int i = 0; i < VEC; ++i) v[i] = (float)hv[i];
  float mx = -3.0e38f;
#pragma unroll
  for (int i = 0; i < VEC; ++i) mx = fmaxf(mx, v[i]);
  mx = wave_red_max(mx);
  if (lane == 0) red[wave] = mx;
  __syncthreads();
  mx = fmaxf(fmaxf(red[0], red[1]), fmaxf(red[2], red[3]));
  __syncthreads();
  float s = 0.f;
#pragma unroll
  for (int i = 0; i < VEC; ++i) {
    v[i] = __expf(v[i] - mx);
    s += v[i];
  }
  s = wave_red_sum(s);
  if (lane == 0) red[wave] = s;
  __syncthreads();
  s = red[0] + red[1] + red[2] + red[3];
  const float inv = 1.f / s;
  hvec res;
#pragma unroll
  for (int i = 0; i < VEC; ++i) res[i] = (half_t)(v[i] * inv);
  *reinterpret_cast<hvec*>(p) = res;
}

// ------------------------------------------------------------- fp32 -> f16
__global__ void f32_to_f16_k(const float* __restrict__ in, half_t* __restrict__ out, int n4) {
  const int i = blockIdx.x * 256 + threadIdx.x;
  if (i < n4) {
    const float4 f = reinterpret_cast<const float4*>(in)[i];
    half4v h; h[0] = (half_t)f.x; h[1] = (half_t)f.y; h[2] = (half_t)f.z; h[3] = (half_t)f.w;
    reinterpret_cast<half4v*>(out)[i] = h;
  }
}

// ------------------------------------------------------------- workspace map
constexpr size_t OFF_XH    = 0;
constexpr size_t OFF_YH    = OFF_XH    + (size_t)Bc*Tc*Cc*2;
constexpr size_t OFF_WQ    = OFF_YH    + (size_t)Bc*Mc*Cc*2;
constexpr size_t OFF_WP    = OFF_WQ    + (size_t)3*Cc*Cc*2;
constexpr size_t OFF_QX    = OFF_WP    + (size_t)Cc*Cc*2;
constexpr size_t OFF_KX    = OFF_QX    + (size_t)Bc*Hc*Tc*Dc*2;
constexpr size_t OFF_VXT   = OFF_KX    + (size_t)Bc*Hc*Tc*Dc*2;  // [B,H,D,T]
constexpr size_t OFF_QY    = OFF_VXT   + (size_t)Bc*Hc*Tc*Dc*2;
constexpr size_t OFF_KY    = OFF_QY    + (size_t)Bc*Hc*Mc*Dc*2;
constexpr size_t OFF_VYT   = OFF_KY    + (size_t)Bc*Hc*Mc*Dc*2;  // [B,H,D,M]
constexpr size_t OFF_CATT  = OFF_VYT   + (size_t)Bc*Hc*Mc*Dc*2;  // [B,H,T,M]
constexpr size_t OFF_CATTT = OFF_CATT  + (size_t)Bc*Hc*Tc*Mc*2;  // [B,H,T,M]
constexpr size_t OFF_CV2   = OFF_CATTT + (size_t)Bc*Hc*Tc*Mc*2;  // [B,T,C] f16
constexpr size_t OFF_DH    = OFF_CV2   + (size_t)Bc*Tc*Cc*2;     // [B,T,C] f16
constexpr size_t OFF_PO    = OFF_DH    + (size_t)Bc*Tc*Cc*2;     // [2][B,T,C] f32
constexpr size_t OFF_ML    = OFF_PO    + (size_t)2*Bc*Tc*Cc*4;   // [2*BH,T] float2
// total ~188 MB

extern "C" void kernel_launch(void* const* d_in, const int* in_sizes, int n_in,
                              void* d_out, int out_size, void* d_ws, size_t ws_size,
                              hipStream_t stream) {
  const float* x      = (const float*)d_in[0];
  const float* y      = (const float*)d_in[1];
  const int*   mask   = (const int*)  d_in[2];
  const float* qkv_b  = (const float*)d_in[4];
  const float* proj_b = (const float*)d_in[6];
  float* out = (float*)d_out;
  char* ws = (char*)d_ws;

  half_t* XH    = (half_t*)(ws + OFF_XH);
  half_t* YH    = (half_t*)(ws + OFF_YH);
  half_t* WQ    = (half_t*)(ws + OFF_WQ);
  half_t* WP    = (half_t*)(ws + OFF_WP);
  half_t* QX    = (half_t*)(ws + OFF_QX);
  half_t* KX    = (half_t*)(ws + OFF_KX);
  half_t* VXT   = (half_t*)(ws + OFF_VXT);
  half_t* QY    = (half_t*)(ws + OFF_QY);
  half_t* KY    = (half_t*)(ws + OFF_KY);
  half_t* VYT   = (half_t*)(ws + OFF_VYT);
  half_t* CATT  = (half_t*)(ws + OFF_CATT);
  half_t* CATTT = (half_t*)(ws + OFF_CATTT);
  half_t* CV2   = (half_t*)(ws + OFF_CV2);
  half_t* DH    = (half_t*)(ws + OFF_DH);
  float*  PO    = (float*) (ws + OFF_PO);
  float2* ML    = (float2*)(ws + OFF_ML);

  // fp32 -> f16 converts
  f32_to_f16_k<<<(Bc*Tc*Cc/4 + 255) / 256, 256, 0, stream>>>(x, XH, Bc*Tc*Cc/4);
  f32_to_f16_k<<<(Bc*Mc*Cc/4 + 255) / 256, 256, 0, stream>>>(y, YH, Bc*Mc*Cc/4);
  f32_to_f16_k<<<(3*Cc*Cc/4 + 255) / 256, 256, 0, stream>>>((const float*)d_in[3], WQ, 3*Cc*Cc/4);
  f32_to_f16_k<<<(Cc*Cc/4 + 255) / 256, 256, 0, stream>>>((const float*)d_in[5], WP, Cc*Cc/4);

  // qkv projections
  {
    EpiParams ep{}; ep.h0 = QX; ep.h1 = KX; ep.h2 = VXT; ep.bias = qkv_b; ep.seq = Tc;
    gemm_nt<128,128,2,2,EPI_QKV><<<dim3(12, 32, 1), 256, 0, stream>>>(
        XH, WQ, Cc, Cc, Cc, 0, 0, ep);
  }
  {
    EpiParams ep{}; ep.h0 = QY; ep.h1 = KY; ep.h2 = VYT; ep.bias = qkv_b; ep.seq = Mc;
    gemm_nt<64,128,2,2,EPI_QKV><<<dim3(12, 32, 1), 256, 0, stream>>>(
        YH, WQ, Cc, Cc, Cc, 0, 0, ep);
  }
  // catt_x2y[t,m] = q_x(scaled)[t] . k_y[m]
  {
    EpiParams ep{}; ep.h0 = CATT; ep.scale = 1.f; ep.ldc = Mc; ep.bstride = (long)Tc*Mc;
    gemm_nt<128,128,2,2,EPI_F16STORE><<<dim3(8, 16, Bc*Hc), 256, 0, stream>>>(
        QX, KY, Dc, Dc, Dc, (long)Tc*Dc, (long)Mc*Dc, ep);
  }
  // catt_y2x^T[s,m] = k_x[s] . q_y(scaled)[m]
  {
    EpiParams ep{}; ep.h0 = CATTT; ep.scale = 1.f; ep.ldc = Mc; ep.bstride = (long)Tc*Mc;
    gemm_nt<128,128,2,2,EPI_F16STORE><<<dim3(8, 16, Bc*Hc), 256, 0, stream>>>(
        KX, QY, Dc, Dc, Dc, (long)Tc*Dc, (long)Mc*Dc, ep);
  }

  // Second attention fully fused, split over 2 s-halves (4 blocks/CU).
  flash_chained<<<dim3(Tc/64, Bc*Hc, 2), 256, 0, stream>>>(
      CATT, CATTT, VXT, mask, PO, ML);
  combine_k<<<(int)(BTC/4/256), 256, 0, stream>>>(PO, ML, CV2);

  // First attention: softmax over m (in-place on CATT, raw scores consumed)
  softmax_rows<Mc><<<Bc*Hc*Tc, 256, 0, stream>>>(CATT);
  // cval_x2y[t,d] = sum_m P[t,m]*vT_y[d,m]; DH = cval_x2y - CV2
  {
    EpiParams ep{}; ep.h0 = DH; ep.h1 = CV2;
    gemm_nt<32,64,2,2,EPI_CVALDIFF><<<dim3(1, 64, Bc*Hc), 256, 0, stream>>>(
        CATT, VYT, Mc, Mc, Mc, (long)Tc*Mc, (long)Dc*Mc, ep);
  }
  // out = diff @ proj_w^T + proj_b
  {
    EpiParams ep{}; ep.f0 = out; ep.bias = proj_b;
    gemm_nt<128,64,2,2,EPI_PROJ><<<dim3(8, 32, 1), 256, 0, stream>>>(
        DH, WP, Cc, Cc, Cc, 0, 0, ep);
  }
}

// Round 7
// 308.452 us; speedup vs baseline: 1.8787x; 1.8787x over previous
//
#include <hip/hip_runtime.h>

// CrossAttentionPro on MI355X — Round 6: RANK-64 FACTORIZATION.
// chained = scale^3 (Qx Ky^T)(Qy Kx^T) = Qx (scale^3 Ky^T Qy) Kx^T,
// W = Ky^T Qy is 64x64/head -> chained attention becomes a standard
// D=64 flash attention with Q' = Qx W. First attention likewise runs as
// flash on (Qxs, Ky, Vy). CATT/CATTT/CH never materialized.
// Total MFMA work drops ~172 -> ~40 GF; the R5 LDS-bound K=1024-in-flash
// loop is deleted.

typedef _Float16 half_t;
typedef _Float16 half8 __attribute__((ext_vector_type(8)));
typedef _Float16 half4v __attribute__((ext_vector_type(4)));
typedef float floatx4 __attribute__((ext_vector_type(4)));

constexpr int Bc = 2, Tc = 2048, Mc = 1024, Cc = 512, Hc = 8, Dc = 64;

enum { EPI_F16STORE = 0, EPI_QKV_X = 1, EPI_QKV_Y = 2, EPI_PROJ = 3 };

struct EpiParams {
  half_t* h0;
  half_t* h1;
  half_t* h2;
  half_t* h3;
  float* f0;
  const float* bias;
  float scale;
  int ldc;
  long bstride;
  int seq;
};

// async global->LDS, 16B per lane; dst must be wave-uniform base + lane*16.
__device__ __forceinline__ void gld_lds16(const half_t* g, half_t* l) {
  __builtin_amdgcn_global_load_lds(
      (const __attribute__((address_space(1))) void*)g,
      (__attribute__((address_space(3))) void*)l, 16, 0, 0);
}

// ---------------------------------------------------------------- GEMM (NT)
// R2-proven: C[r,c] = sum_k A[r,k]*Bt[c,k], BK=32 swizzled async staging
// (measured 0 bank conflicts), direct per-element epilogue.
template <int BM, int BN, int WMG, int WNG, int EPI>
__global__ __launch_bounds__(256) void gemm_nt(
    const half_t* __restrict__ A, const half_t* __restrict__ Bt,
    int K, int lda, int ldb, long bsA, long bsB, EpiParams ep)
{
  constexpr int BK = 32;
  constexpr int WTM = BM / WMG, WTN = BN / WNG;
  constexpr int MI = WTM / 16, NI = WTN / 16;
  constexpr int ACHUNKS = BM * 4;
  constexpr int BCHUNKS = BN * 4;
  __shared__ __align__(16) half_t As[BM * BK];
  __shared__ __align__(16) half_t Bs[BN * BK];

  const int tid = threadIdx.x;
  const int lane = tid & 63;
  const int wave = tid >> 6;
  const int wm = wave / WNG, wn = wave % WNG;
  const int r16 = lane & 15, g = lane >> 4;
  const int z = blockIdx.z;
  const long m0 = (long)blockIdx.y * BM;
  const long n0 = (long)blockIdx.x * BN;
  const half_t* Abase = A + (long)z * bsA + m0 * (long)lda;
  const half_t* Bbase = Bt + (long)z * bsB + n0 * (long)ldb;

  const int rA = wm * WTM + r16;
  const int rB = wn * WTN + r16;
  const int swA = (g ^ ((rA >> 1) & 3)) * 8;
  const int swB = (g ^ ((rB >> 1) & 3)) * 8;

  floatx4 acc[MI][NI];
#pragma unroll
  for (int mi = 0; mi < MI; ++mi)
#pragma unroll
    for (int ni = 0; ni < NI; ++ni)
      acc[mi][ni] = floatx4{0.f, 0.f, 0.f, 0.f};

  for (int kt = 0; kt < K; kt += BK) {
#pragma unroll
    for (int i = 0; i < (ACHUNKS + 255) / 256; ++i) {
      const int c = tid + i * 256;
      if (ACHUNKS % 256 == 0 || c < ACHUNKS) {
        const int row = c >> 2, js = c & 3;
        const int jg = js ^ ((row >> 1) & 3);
        gld_lds16(Abase + (long)row * lda + kt + jg * 8, As + c * 8);
      }
    }
#pragma unroll
    for (int i = 0; i < (BCHUNKS + 255) / 256; ++i) {
      const int c = tid + i * 256;
      if (BCHUNKS % 256 == 0 || c < BCHUNKS) {
        const int row = c >> 2, js = c & 3;
        const int jg = js ^ ((row >> 1) & 3);
        gld_lds16(Bbase + (long)row * ldb + kt + jg * 8, Bs + c * 8);
      }
    }
    __syncthreads();
    half8 aF[MI], bF[NI];
#pragma unroll
    for (int mi = 0; mi < MI; ++mi)
      aF[mi] = *reinterpret_cast<const half8*>(&As[(rA + mi * 16) * BK + swA]);
#pragma unroll
    for (int ni = 0; ni < NI; ++ni)
      bF[ni] = *reinterpret_cast<const half8*>(&Bs[(rB + ni * 16) * BK + swB]);
#pragma unroll
    for (int mi = 0; mi < MI; ++mi)
#pragma unroll
      for (int ni = 0; ni < NI; ++ni)
        acc[mi][ni] = __builtin_amdgcn_mfma_f32_16x16x32_f16(aF[mi], bF[ni], acc[mi][ni], 0, 0, 0);
    __syncthreads();
  }

  // epilogue: C/D layout col=lane&15, row=(lane>>4)*4+reg  [m89-verified]
#pragma unroll
  for (int mi = 0; mi < MI; ++mi) {
#pragma unroll
    for (int ni = 0; ni < NI; ++ni) {
#pragma unroll
      for (int reg = 0; reg < 4; ++reg) {
        const int r = (int)m0 + wm * WTM + mi * 16 + g * 4 + reg;
        const int c = (int)n0 + wn * WTN + ni * 16 + r16;
        const float v = acc[mi][ni][reg];
        if constexpr (EPI == EPI_F16STORE) {
          ep.h0[(long)z * ep.bstride + (long)r * ep.ldc + c] = (half_t)(v * ep.scale);
        } else if constexpr (EPI == EPI_QKV_X) {
          const float val = v + ep.bias[c];
          const int which = c >> 9;     // 0=q 1=k 2=v
          const int cc2 = c & 511;
          const int h = cc2 >> 6, d = cc2 & 63;
          const int b = r / ep.seq, t = r - b * ep.seq;
          const long bh = (long)(b * Hc + h);
          if (which == 0)      ep.h0[(bh * ep.seq + t) * Dc + d] = (half_t)(val * 0.125f); // QXs
          else if (which == 1) ep.h1[(bh * ep.seq + t) * Dc + d] = (half_t)val;            // KX
          else                 ep.h2[(bh * Dc + d) * ep.seq + t] = (half_t)val;            // VXT
        } else if constexpr (EPI == EPI_QKV_Y) {
          const float val = v + ep.bias[c];
          const int which = c >> 9;
          const int cc2 = c & 511;
          const int h = cc2 >> 6, d = cc2 & 63;
          const int b = r / ep.seq, t = r - b * ep.seq;
          const long bh = (long)(b * Hc + h);
          if (which == 0)      ep.h0[(bh * Dc + d) * ep.seq + t] = (half_t)(val * 0.125f); // QYTs
          else if (which == 1) { ep.h1[(bh * ep.seq + t) * Dc + d] = (half_t)val;          // KY
                                 ep.h3[(bh * Dc + d) * ep.seq + t] = (half_t)val; }        // KYT
          else                 ep.h2[(bh * Dc + d) * ep.seq + t] = (half_t)val;            // VYT
        } else {  // EPI_PROJ
          ep.f0[(long)r * Cc + c] = v + ep.bias[c];
        }
      }
    }
  }
}

// ------------------------------------------------------- flash attention
// Standard flash, D=64, Q rows = Tc. Per block: 64 q-rows of one z;
// s-tiles of 128. Q A-frags live in registers (loaded once, global).
// K-tile [128][64] and V^T-tile [64][128] staged via global_load_lds with
// XOR-chunk swizzle (2-way reads, free). Softmax/PV register patterns are
// the R4/R5-verified ones. EPI_AV: 0 -> out=O/l; 1 -> out=O/l - cv_in.
template <int EPI_AV, bool MASKED>
__global__ __launch_bounds__(256) void flash_attn(
    const half_t* __restrict__ Qp,   // [z][Tc][64]
    const half_t* __restrict__ Kp,   // [z][Slen][64]
    const half_t* __restrict__ Vp,   // [z][64][Slen]  (V^T)
    const int* __restrict__ mask,    // [Tc][Slen] or null
    half_t* __restrict__ outp,       // [B,T,C] f16
    const half_t* __restrict__ cv_in,
    int Slen)
{
  constexpr int ST = 128;
  __shared__ __align__(16) half_t Ks[128 * 64];    // 16 KB
  __shared__ __align__(16) half_t Vs[64 * 128];    // 16 KB
  __shared__ __align__(16) half_t Ps[4 * 16 * 136];// 17 KB, per-wave slabs

  const int tid = threadIdx.x, lane = tid & 63, w = tid >> 6;
  const int r16 = lane & 15, g = lane >> 4;
  const int z = blockIdx.y, q0 = blockIdx.x * 64;
  const int b = z >> 3, h = z & 7;
  const half_t* Qz = Qp + ((long)z * Tc + q0) * 64;
  const half_t* Kz = Kp + (long)z * Slen * 64;
  const half_t* Vz = Vp + (long)z * 64 * Slen;

  // Q fragments: A-layout row=r16 (q = q0+w*16+r16), k = kt*32 + g*8
  const half8 aQ0 = *reinterpret_cast<const half8*>(Qz + (w * 16 + r16) * 64 + g * 8);
  const half8 aQ1 = *reinterpret_cast<const half8*>(Qz + (w * 16 + r16) * 64 + 32 + g * 8);

  floatx4 oacc[4];
#pragma unroll
  for (int no = 0; no < 4; ++no) oacc[no] = floatx4{0.f, 0.f, 0.f, 0.f};
  float mrun[4], lrun[4];
#pragma unroll
  for (int reg = 0; reg < 4; ++reg) { mrun[reg] = -1e30f; lrun[reg] = 0.f; }

  for (int s0 = 0; s0 < Slen; s0 += ST) {
    // stage K: 128 rows x 64 halfs, 8 chunks/row, slot js holds global chunk js^(row&7)
#pragma unroll
    for (int i = 0; i < 4; ++i) {
      const int c = tid + i * 256;
      const int row = c >> 3, js = c & 7;
      const int jg = js ^ (row & 7);
      gld_lds16(Kz + (long)(s0 + row) * 64 + jg * 8, Ks + c * 8);
    }
    // stage V^T: 64 rows x 128 halfs, 16 chunks/row, slot js holds js^(row&15)
#pragma unroll
    for (int i = 0; i < 4; ++i) {
      const int c = tid + i * 256;
      const int row = c >> 4, js = c & 15;
      const int jg = js ^ (row & 15);
      gld_lds16(Vz + (long)row * Slen + s0 + jg * 8, Vs + c * 8);
    }
    __syncthreads();

    // S = Q K^T (K-dim 64 = 2 MFMA steps)
    floatx4 sacc[8];
#pragma unroll
    for (int ni = 0; ni < 8; ++ni) sacc[ni] = floatx4{0.f, 0.f, 0.f, 0.f};
#pragma unroll
    for (int ni = 0; ni < 8; ++ni) {
      const int rB = ni * 16 + r16;
      const half8 b0 = *reinterpret_cast<const half8*>(&Ks[rB * 64 + ((g) ^ (rB & 7)) * 8]);
      sacc[ni] = __builtin_amdgcn_mfma_f32_16x16x32_f16(aQ0, b0, sacc[ni], 0, 0, 0);
      const half8 b1 = *reinterpret_cast<const half8*>(&Ks[rB * 64 + ((4 + g) ^ (rB & 7)) * 8]);
      sacc[ni] = __builtin_amdgcn_mfma_f32_16x16x32_f16(aQ1, b1, sacc[ni], 0, 0, 0);
    }

    // masked online softmax (C-layout: row=g*4+reg, col=ni*16+r16) [R4-verified]
    float sv[8][4];
#pragma unroll
    for (int ni = 0; ni < 8; ++ni)
#pragma unroll
      for (int reg = 0; reg < 4; ++reg) sv[ni][reg] = sacc[ni][reg];
    if constexpr (MASKED) {
#pragma unroll
      for (int reg = 0; reg < 4; ++reg) {
        const long trow = (long)(q0 + w * 16 + g * 4 + reg) * Slen + s0;
#pragma unroll
        for (int ni = 0; ni < 8; ++ni)
          if (mask[trow + ni * 16 + r16] == 0) sv[ni][reg] = -__builtin_inff();
      }
    }
#pragma unroll
    for (int reg = 0; reg < 4; ++reg) {
      float tm = sv[0][reg];
#pragma unroll
      for (int ni = 1; ni < 8; ++ni) tm = fmaxf(tm, sv[ni][reg]);
      tm = fmaxf(tm, __shfl_xor(tm, 1));
      tm = fmaxf(tm, __shfl_xor(tm, 2));
      tm = fmaxf(tm, __shfl_xor(tm, 4));
      tm = fmaxf(tm, __shfl_xor(tm, 8));
      const float mnew = fmaxf(mrun[reg], tm);
      const float alpha = __expf(mrun[reg] - mnew);
      mrun[reg] = mnew;
      float ps = 0.f;
#pragma unroll
      for (int ni = 0; ni < 8; ++ni) {
        const float e = __expf(sv[ni][reg] - mnew);
        ps += e;
        Ps[w * 2176 + (g * 4 + reg) * 136 + ni * 16 + r16] = (half_t)e;
      }
      ps += __shfl_xor(ps, 1);
      ps += __shfl_xor(ps, 2);
      ps += __shfl_xor(ps, 4);
      ps += __shfl_xor(ps, 8);
      lrun[reg] = lrun[reg] * alpha + ps;
#pragma unroll
      for (int no = 0; no < 4; ++no) oacc[no][reg] *= alpha;
    }

    // PV: O[t,d] += P[t,s] V^T[d,s]
#pragma unroll
    for (int ks2 = 0; ks2 < 4; ++ks2) {
      const half8 aP = *reinterpret_cast<const half8*>(
          &Ps[w * 2176 + r16 * 136 + ks2 * 32 + g * 8]);
#pragma unroll
      for (int no = 0; no < 4; ++no) {
        const int rV = no * 16 + r16;
        const half8 bV = *reinterpret_cast<const half8*>(
            &Vs[rV * 128 + ((ks2 * 4 + g) ^ (rV & 15)) * 8]);
        oacc[no] = __builtin_amdgcn_mfma_f32_16x16x32_f16(aP, bV, oacc[no], 0, 0, 0);
      }
    }
    __syncthreads();
  }

  // epilogue: O/l -> out[b, t, h*64+d]
#pragma unroll
  for (int reg = 0; reg < 4; ++reg) {
    const float linv = 1.f / lrun[reg];
    const int t = q0 + w * 16 + g * 4 + reg;
#pragma unroll
    for (int no = 0; no < 4; ++no) {
      const int d = no * 16 + r16;
      const long idx = ((long)(b * Tc + t)) * Cc + h * 64 + d;
      const float val = oacc[no][reg] * linv;
      if constexpr (EPI_AV == 0) outp[idx] = (half_t)val;
      else                       outp[idx] = (half_t)(val - (float)cv_in[idx]);
    }
  }
}

// ------------------------------------------------------------- fp32 -> f16
__global__ void f32_to_f16_k(const float* __restrict__ in, half_t* __restrict__ out, int n4) {
  const int i = blockIdx.x * 256 + threadIdx.x;
  if (i < n4) {
    const float4 f = reinterpret_cast<const float4*>(in)[i];
    half4v h; h[0] = (half_t)f.x; h[1] = (half_t)f.y; h[2] = (half_t)f.z; h[3] = (half_t)f.w;
    reinterpret_cast<half4v*>(out)[i] = h;
  }
}

// ------------------------------------------------------------- workspace map
constexpr size_t OFF_XH   = 0;                                   // [B*T,C] f16
constexpr size_t OFF_YH   = OFF_XH   + (size_t)Bc*Tc*Cc*2;
constexpr size_t OFF_WQ   = OFF_YH   + (size_t)Bc*Mc*Cc*2;
constexpr size_t OFF_WP   = OFF_WQ   + (size_t)3*Cc*Cc*2;
constexpr size_t OFF_QX   = OFF_WP   + (size_t)Cc*Cc*2;          // [z,T,D] scaled
constexpr size_t OFF_KX   = OFF_QX   + (size_t)Bc*Hc*Tc*Dc*2;    // [z,T,D]
constexpr size_t OFF_VXT  = OFF_KX   + (size_t)Bc*Hc*Tc*Dc*2;    // [z,D,T]
constexpr size_t OFF_QYT  = OFF_VXT  + (size_t)Bc*Hc*Tc*Dc*2;    // [z,D,M] scaled
constexpr size_t OFF_KY   = OFF_QYT  + (size_t)Bc*Hc*Mc*Dc*2;    // [z,M,D]
constexpr size_t OFF_KYT  = OFF_KY   + (size_t)Bc*Hc*Mc*Dc*2;    // [z,D,M]
constexpr size_t OFF_VYT  = OFF_KYT  + (size_t)Bc*Hc*Mc*Dc*2;    // [z,D,M]
constexpr size_t OFF_WT   = OFF_VYT  + (size_t)Bc*Hc*Mc*Dc*2;    // [z,64,64]
constexpr size_t OFF_Q2   = OFF_WT   + (size_t)Bc*Hc*Dc*Dc*2;    // [z,T,D]
constexpr size_t OFF_CV2  = OFF_Q2   + (size_t)Bc*Hc*Tc*Dc*2;    // [B,T,C]
constexpr size_t OFF_DH   = OFF_CV2  + (size_t)Bc*Tc*Cc*2;       // [B,T,C]
// total ~44 MB

extern "C" void kernel_launch(void* const* d_in, const int* in_sizes, int n_in,
                              void* d_out, int out_size, void* d_ws, size_t ws_size,
                              hipStream_t stream) {
  const float* x      = (const float*)d_in[0];
  const float* y      = (const float*)d_in[1];
  const int*   mask   = (const int*)  d_in[2];
  const float* qkv_b  = (const float*)d_in[4];
  const float* proj_b = (const float*)d_in[6];
  float* out = (float*)d_out;
  char* ws = (char*)d_ws;

  half_t* XH   = (half_t*)(ws + OFF_XH);
  half_t* YH   = (half_t*)(ws + OFF_YH);
  half_t* WQ   = (half_t*)(ws + OFF_WQ);
  half_t* WP   = (half_t*)(ws + OFF_WP);
  half_t* QX   = (half_t*)(ws + OFF_QX);
  half_t* KX   = (half_t*)(ws + OFF_KX);
  half_t* VXT  = (half_t*)(ws + OFF_VXT);
  half_t* QYT  = (half_t*)(ws + OFF_QYT);
  half_t* KY   = (half_t*)(ws + OFF_KY);
  half_t* KYT  = (half_t*)(ws + OFF_KYT);
  half_t* VYT  = (half_t*)(ws + OFF_VYT);
  half_t* WT   = (half_t*)(ws + OFF_WT);
  half_t* Q2   = (half_t*)(ws + OFF_Q2);
  half_t* CV2  = (half_t*)(ws + OFF_CV2);
  half_t* DH   = (half_t*)(ws + OFF_DH);

  // fp32 -> f16 converts
  f32_to_f16_k<<<(Bc*Tc*Cc/4 + 255) / 256, 256, 0, stream>>>(x, XH, Bc*Tc*Cc/4);
  f32_to_f16_k<<<(Bc*Mc*Cc/4 + 255) / 256, 256, 0, stream>>>(y, YH, Bc*Mc*Cc/4);
  f32_to_f16_k<<<(3*Cc*Cc/4 + 255) / 256, 256, 0, stream>>>((const float*)d_in[3], WQ, 3*Cc*Cc/4);
  f32_to_f16_k<<<(Cc*Cc/4 + 255) / 256, 256, 0, stream>>>((const float*)d_in[5], WP, Cc*Cc/4);

  // qkv projections
  {
    EpiParams ep{}; ep.h0 = QX; ep.h1 = KX; ep.h2 = VXT; ep.bias = qkv_b; ep.seq = Tc;
    gemm_nt<128,128,2,2,EPI_QKV_X><<<dim3(12, 32, 1), 256, 0, stream>>>(
        XH, WQ, Cc, Cc, Cc, 0, 0, ep);
  }
  {
    EpiParams ep{}; ep.h0 = QYT; ep.h1 = KY; ep.h2 = VYT; ep.h3 = KYT;
    ep.bias = qkv_b; ep.seq = Mc;
    gemm_nt<64,128,2,2,EPI_QKV_Y><<<dim3(12, 32, 1), 256, 0, stream>>>(
        YH, WQ, Cc, Cc, Cc, 0, 0, ep);
  }

  // WT[z][d2][d1] = 0.125 * sum_m QYTs[d2,m] KYT[d1,m]  (total scale^3 w/ QYTs,QXs)
  {
    EpiParams ep{}; ep.h0 = WT; ep.scale = 0.125f; ep.ldc = 64; ep.bstride = 64 * 64;
    gemm_nt<64,64,2,2,EPI_F16STORE><<<dim3(1, 1, Bc*Hc), 256, 0, stream>>>(
        QYT, KYT, Mc, Mc, Mc, (long)Dc*Mc, (long)Dc*Mc, ep);
  }
  // Q2[z][t][d2] = sum_d1 QXs[t,d1] WT[d2,d1]
  {
    EpiParams ep{}; ep.h0 = Q2; ep.scale = 1.f; ep.ldc = 64; ep.bstride = (long)Tc * 64;
    gemm_nt<128,64,2,2,EPI_F16STORE><<<dim3(1, Tc/128, Bc*Hc), 256, 0, stream>>>(
        QX, WT, Dc, Dc, Dc, (long)Tc*Dc, (long)64*64, ep);
  }

  // chained attention (masked): softmax(Q2 Kx^T) Vx -> CV2
  flash_attn<0, true><<<dim3(Tc/64, Bc*Hc), 256, 0, stream>>>(
      Q2, KX, VXT, mask, CV2, nullptr, Tc);
  // first attention: softmax(QXs Ky^T) Vy - CV2 -> DH
  flash_attn<1, false><<<dim3(Tc/64, Bc*Hc), 256, 0, stream>>>(
      QX, KY, VYT, nullptr, DH, CV2, Mc);

  // out = DH @ proj_w^T + proj_b
  {
    EpiParams ep{}; ep.f0 = out; ep.bias = proj_b;
    gemm_nt<128,64,2,2,EPI_PROJ><<<dim3(8, 32, 1), 256, 0, stream>>>(
        DH, WP, Cc, Cc, Cc, 0, 0, ep);
  }
}

// Round 8
// 255.262 us; speedup vs baseline: 2.2701x; 1.2084x over previous
//
#include <hip/hip_runtime.h>

// CrossAttentionPro on MI355X — Round 7:
//  R6 rank-64 pipeline +
//  + bit-packed mask (MPK[t][tile][r16] byte = 8 ni-bits): 32x less mask
//    traffic, 512 KB total (L2-resident), 4 byte-loads/thread/s-tile.
//  + z-local XCD swizzle in flash (z = (b&7)*2+((b>>3)&1)): K/V working
//    set 1 MB/XCD -> L2-resident staging.
// chained = Qx (scale^3 Ky^T Qy) Kx^T  (W is 64x64/head) -> both
// attentions are standard D=64 flash; CATT/CATTT/CH never materialized.

typedef _Float16 half_t;
typedef _Float16 half8 __attribute__((ext_vector_type(8)));
typedef _Float16 half4v __attribute__((ext_vector_type(4)));
typedef float floatx4 __attribute__((ext_vector_type(4)));

constexpr int Bc = 2, Tc = 2048, Mc = 1024, Cc = 512, Hc = 8, Dc = 64;

enum { EPI_F16STORE = 0, EPI_QKV_X = 1, EPI_QKV_Y = 2, EPI_PROJ = 3 };

struct EpiParams {
  half_t* h0;
  half_t* h1;
  half_t* h2;
  half_t* h3;
  float* f0;
  const float* bias;
  float scale;
  int ldc;
  long bstride;
  int seq;
};

// async global->LDS, 16B per lane; dst must be wave-uniform base + lane*16.
__device__ __forceinline__ void gld_lds16(const half_t* g, half_t* l) {
  __builtin_amdgcn_global_load_lds(
      (const __attribute__((address_space(1))) void*)g,
      (__attribute__((address_space(3))) void*)l, 16, 0, 0);
}

// ---------------------------------------------------------------- GEMM (NT)
// R2-proven: C[r,c] = sum_k A[r,k]*Bt[c,k], BK=32 swizzled async staging
// (measured 0 bank conflicts), direct per-element epilogue.
template <int BM, int BN, int WMG, int WNG, int EPI>
__global__ __launch_bounds__(256) void gemm_nt(
    const half_t* __restrict__ A, const half_t* __restrict__ Bt,
    int K, int lda, int ldb, long bsA, long bsB, EpiParams ep)
{
  constexpr int BK = 32;
  constexpr int WTM = BM / WMG, WTN = BN / WNG;
  constexpr int MI = WTM / 16, NI = WTN / 16;
  constexpr int ACHUNKS = BM * 4;
  constexpr int BCHUNKS = BN * 4;
  __shared__ __align__(16) half_t As[BM * BK];
  __shared__ __align__(16) half_t Bs[BN * BK];

  const int tid = threadIdx.x;
  const int lane = tid & 63;
  const int wave = tid >> 6;
  const int wm = wave / WNG, wn = wave % WNG;
  const int r16 = lane & 15, g = lane >> 4;
  const int z = blockIdx.z;
  const long m0 = (long)blockIdx.y * BM;
  const long n0 = (long)blockIdx.x * BN;
  const half_t* Abase = A + (long)z * bsA + m0 * (long)lda;
  const half_t* Bbase = Bt + (long)z * bsB + n0 * (long)ldb;

  const int rA = wm * WTM + r16;
  const int rB = wn * WTN + r16;
  const int swA = (g ^ ((rA >> 1) & 3)) * 8;
  const int swB = (g ^ ((rB >> 1) & 3)) * 8;

  floatx4 acc[MI][NI];
#pragma unroll
  for (int mi = 0; mi < MI; ++mi)
#pragma unroll
    for (int ni = 0; ni < NI; ++ni)
      acc[mi][ni] = floatx4{0.f, 0.f, 0.f, 0.f};

  for (int kt = 0; kt < K; kt += BK) {
#pragma unroll
    for (int i = 0; i < (ACHUNKS + 255) / 256; ++i) {
      const int c = tid + i * 256;
      if (ACHUNKS % 256 == 0 || c < ACHUNKS) {
        const int row = c >> 2, js = c & 3;
        const int jg = js ^ ((row >> 1) & 3);
        gld_lds16(Abase + (long)row * lda + kt + jg * 8, As + c * 8);
      }
    }
#pragma unroll
    for (int i = 0; i < (BCHUNKS + 255) / 256; ++i) {
      const int c = tid + i * 256;
      if (BCHUNKS % 256 == 0 || c < BCHUNKS) {
        const int row = c >> 2, js = c & 3;
        const int jg = js ^ ((row >> 1) & 3);
        gld_lds16(Bbase + (long)row * ldb + kt + jg * 8, Bs + c * 8);
      }
    }
    __syncthreads();
    half8 aF[MI], bF[NI];
#pragma unroll
    for (int mi = 0; mi < MI; ++mi)
      aF[mi] = *reinterpret_cast<const half8*>(&As[(rA + mi * 16) * BK + swA]);
#pragma unroll
    for (int ni = 0; ni < NI; ++ni)
      bF[ni] = *reinterpret_cast<const half8*>(&Bs[(rB + ni * 16) * BK + swB]);
#pragma unroll
    for (int mi = 0; mi < MI; ++mi)
#pragma unroll
      for (int ni = 0; ni < NI; ++ni)
        acc[mi][ni] = __builtin_amdgcn_mfma_f32_16x16x32_f16(aF[mi], bF[ni], acc[mi][ni], 0, 0, 0);
    __syncthreads();
  }

  // epilogue: C/D layout col=lane&15, row=(lane>>4)*4+reg  [m89-verified]
#pragma unroll
  for (int mi = 0; mi < MI; ++mi) {
#pragma unroll
    for (int ni = 0; ni < NI; ++ni) {
#pragma unroll
      for (int reg = 0; reg < 4; ++reg) {
        const int r = (int)m0 + wm * WTM + mi * 16 + g * 4 + reg;
        const int c = (int)n0 + wn * WTN + ni * 16 + r16;
        const float v = acc[mi][ni][reg];
        if constexpr (EPI == EPI_F16STORE) {
          ep.h0[(long)z * ep.bstride + (long)r * ep.ldc + c] = (half_t)(v * ep.scale);
        } else if constexpr (EPI == EPI_QKV_X) {
          const float val = v + ep.bias[c];
          const int which = c >> 9;     // 0=q 1=k 2=v
          const int cc2 = c & 511;
          const int h = cc2 >> 6, d = cc2 & 63;
          const int b = r / ep.seq, t = r - b * ep.seq;
          const long bh = (long)(b * Hc + h);
          if (which == 0)      ep.h0[(bh * ep.seq + t) * Dc + d] = (half_t)(val * 0.125f); // QXs
          else if (which == 1) ep.h1[(bh * ep.seq + t) * Dc + d] = (half_t)val;            // KX
          else                 ep.h2[(bh * Dc + d) * ep.seq + t] = (half_t)val;            // VXT
        } else if constexpr (EPI == EPI_QKV_Y) {
          const float val = v + ep.bias[c];
          const int which = c >> 9;
          const int cc2 = c & 511;
          const int h = cc2 >> 6, d = cc2 & 63;
          const int b = r / ep.seq, t = r - b * ep.seq;
          const long bh = (long)(b * Hc + h);
          if (which == 0)      ep.h0[(bh * Dc + d) * ep.seq + t] = (half_t)(val * 0.125f); // QYTs
          else if (which == 1) { ep.h1[(bh * ep.seq + t) * Dc + d] = (half_t)val;          // KY
                                 ep.h3[(bh * Dc + d) * ep.seq + t] = (half_t)val; }        // KYT
          else                 ep.h2[(bh * Dc + d) * ep.seq + t] = (half_t)val;            // VYT
        } else {  // EPI_PROJ
          ep.f0[(long)r * Cc + c] = v + ep.bias[c];
        }
      }
    }
  }
}

// ----------------------------------------------------- mask bit-packing
// MPK[t][tile][r16] byte: bit ni = (mask[t][tile*128 + ni*16 + r16] != 0).
__global__ __launch_bounds__(256) void pack_mask(
    const int* __restrict__ mask, unsigned char* __restrict__ mpk)
{
  const int idx = blockIdx.x * 256 + threadIdx.x;   // [0, Tc*16*16)
  const int t = idx >> 8, tile = (idx >> 4) & 15, r16 = idx & 15;
  const int* row = mask + (long)t * Tc + tile * 128 + r16;
  unsigned int b = 0;
#pragma unroll
  for (int ni = 0; ni < 8; ++ni)
    b |= (row[ni * 16] != 0 ? 1u : 0u) << ni;
  mpk[idx] = (unsigned char)b;
}

// ------------------------------------------------------- flash attention
// Standard flash, D=64. 1-D grid 512, z-local XCD swizzle:
// z = (b&7)*2 + ((b>>3)&1), q0 = (b>>4)*64  ->  each XCD (id%8 heuristic)
// hosts 2 z's -> K/V L2-resident. Q A-frags in registers; K/V staged via
// global_load_lds w/ XOR-chunk swizzle. Mask via packed bytes (MPK).
// EPI_AV: 0 -> out=O/l; 1 -> out=O/l - cv_in.
template <int EPI_AV, bool MASKED>
__global__ __launch_bounds__(256) void flash_attn(
    const half_t* __restrict__ Qp,   // [z][Tc][64]
    const half_t* __restrict__ Kp,   // [z][Slen][64]
    const half_t* __restrict__ Vp,   // [z][64][Slen]  (V^T)
    const unsigned char* __restrict__ mpk,  // [Tc][Slen/128][16] or null
    half_t* __restrict__ outp,       // [B,T,C] f16
    const half_t* __restrict__ cv_in,
    int Slen)
{
  constexpr int ST = 128;
  __shared__ __align__(16) half_t Ks[128 * 64];    // 16 KB
  __shared__ __align__(16) half_t Vs[64 * 128];    // 16 KB
  __shared__ __align__(16) half_t Ps[4 * 16 * 136];// 17 KB, per-wave slabs

  const int tid = threadIdx.x, lane = tid & 63, w = tid >> 6;
  const int r16 = lane & 15, g = lane >> 4;
  const int bx = blockIdx.x;
  const int sIdx = bx >> 3;
  const int z = ((bx & 7) << 1) | (sIdx & 1);   // z-local per XCD
  const int q0 = (sIdx >> 1) * 64;
  const int b = z >> 3, h = z & 7;
  const int NT = Slen >> 7;                     // tiles in s
  const half_t* Qz = Qp + ((long)z * Tc + q0) * 64;
  const half_t* Kz = Kp + (long)z * Slen * 64;
  const half_t* Vz = Vp + (long)z * 64 * Slen;

  // Q fragments: A-layout row=r16 (q = q0+w*16+r16), k = kt*32 + g*8
  const half8 aQ0 = *reinterpret_cast<const half8*>(Qz + (w * 16 + r16) * 64 + g * 8);
  const half8 aQ1 = *reinterpret_cast<const half8*>(Qz + (w * 16 + r16) * 64 + 32 + g * 8);

  floatx4 oacc[4];
#pragma unroll
  for (int no = 0; no < 4; ++no) oacc[no] = floatx4{0.f, 0.f, 0.f, 0.f};
  float mrun[4], lrun[4];
#pragma unroll
  for (int reg = 0; reg < 4; ++reg) { mrun[reg] = -1e30f; lrun[reg] = 0.f; }

  for (int s0 = 0; s0 < Slen; s0 += ST) {
    // stage K: 128 rows x 64 halfs, slot js holds global chunk js^(row&7)
#pragma unroll
    for (int i = 0; i < 4; ++i) {
      const int c = tid + i * 256;
      const int row = c >> 3, js = c & 7;
      const int jg = js ^ (row & 7);
      gld_lds16(Kz + (long)(s0 + row) * 64 + jg * 8, Ks + c * 8);
    }
    // stage V^T: 64 rows x 128 halfs, slot js holds js^(row&15)
#pragma unroll
    for (int i = 0; i < 4; ++i) {
      const int c = tid + i * 256;
      const int row = c >> 4, js = c & 15;
      const int jg = js ^ (row & 15);
      gld_lds16(Vz + (long)row * Slen + s0 + jg * 8, Vs + c * 8);
    }
    // mask bytes (issued early; independent of barrier)
    unsigned int mb[4];
    if constexpr (MASKED) {
      const int tile = s0 >> 7;
#pragma unroll
      for (int reg = 0; reg < 4; ++reg) {
        const int t = q0 + w * 16 + g * 4 + reg;
        mb[reg] = mpk[((long)t * NT + tile) * 16 + r16];
      }
    }
    __syncthreads();

    // S = Q K^T (K-dim 64 = 2 MFMA steps)
    floatx4 sacc[8];
#pragma unroll
    for (int ni = 0; ni < 8; ++ni) sacc[ni] = floatx4{0.f, 0.f, 0.f, 0.f};
#pragma unroll
    for (int ni = 0; ni < 8; ++ni) {
      const int rB = ni * 16 + r16;
      const half8 b0 = *reinterpret_cast<const half8*>(&Ks[rB * 64 + ((g) ^ (rB & 7)) * 8]);
      sacc[ni] = __builtin_amdgcn_mfma_f32_16x16x32_f16(aQ0, b0, sacc[ni], 0, 0, 0);
      const half8 b1 = *reinterpret_cast<const half8*>(&Ks[rB * 64 + ((4 + g) ^ (rB & 7)) * 8]);
      sacc[ni] = __builtin_amdgcn_mfma_f32_16x16x32_f16(aQ1, b1, sacc[ni], 0, 0, 0);
    }

    // masked online softmax (C-layout: row=g*4+reg, col=ni*16+r16) [R4-verified]
    float sv[8][4];
#pragma unroll
    for (int ni = 0; ni < 8; ++ni)
#pragma unroll
      for (int reg = 0; reg < 4; ++reg) sv[ni][reg] = sacc[ni][reg];
    if constexpr (MASKED) {
#pragma unroll
      for (int reg = 0; reg < 4; ++reg)
#pragma unroll
        for (int ni = 0; ni < 8; ++ni)
          if (!((mb[reg] >> ni) & 1)) sv[ni][reg] = -__builtin_inff();
    }
#pragma unroll
    for (int reg = 0; reg < 4; ++reg) {
      float tm = sv[0][reg];
#pragma unroll
      for (int ni = 1; ni < 8; ++ni) tm = fmaxf(tm, sv[ni][reg]);
      tm = fmaxf(tm, __shfl_xor(tm, 1));
      tm = fmaxf(tm, __shfl_xor(tm, 2));
      tm = fmaxf(tm, __shfl_xor(tm, 4));
      tm = fmaxf(tm, __shfl_xor(tm, 8));
      const float mnew = fmaxf(mrun[reg], tm);
      const float alpha = __expf(mrun[reg] - mnew);
      mrun[reg] = mnew;
      float ps = 0.f;
#pragma unroll
      for (int ni = 0; ni < 8; ++ni) {
        const float e = __expf(sv[ni][reg] - mnew);
        ps += e;
        Ps[w * 2176 + (g * 4 + reg) * 136 + ni * 16 + r16] = (half_t)e;
      }
      ps += __shfl_xor(ps, 1);
      ps += __shfl_xor(ps, 2);
      ps += __shfl_xor(ps, 4);
      ps += __shfl_xor(ps, 8);
      lrun[reg] = lrun[reg] * alpha + ps;
#pragma unroll
      for (int no = 0; no < 4; ++no) oacc[no][reg] *= alpha;
    }

    // PV: O[t,d] += P[t,s] V^T[d,s]
#pragma unroll
    for (int ks2 = 0; ks2 < 4; ++ks2) {
      const half8 aP = *reinterpret_cast<const half8*>(
          &Ps[w * 2176 + r16 * 136 + ks2 * 32 + g * 8]);
#pragma unroll
      for (int no = 0; no < 4; ++no) {
        const int rV = no * 16 + r16;
        const half8 bV = *reinterpret_cast<const half8*>(
            &Vs[rV * 128 + ((ks2 * 4 + g) ^ (rV & 15)) * 8]);
        oacc[no] = __builtin_amdgcn_mfma_f32_16x16x32_f16(aP, bV, oacc[no], 0, 0, 0);
      }
    }
    __syncthreads();
  }

  // epilogue: O/l -> out[b, t, h*64+d]
#pragma unroll
  for (int reg = 0; reg < 4; ++reg) {
    const float linv = 1.f / lrun[reg];
    const int t = q0 + w * 16 + g * 4 + reg;
#pragma unroll
    for (int no = 0; no < 4; ++no) {
      const int d = no * 16 + r16;
      const long idx = ((long)(b * Tc + t)) * Cc + h * 64 + d;
      const float val = oacc[no][reg] * linv;
      if constexpr (EPI_AV == 0) outp[idx] = (half_t)val;
      else                       outp[idx] = (half_t)(val - (float)cv_in[idx]);
    }
  }
}

// ------------------------------------------------------------- fp32 -> f16
__global__ void f32_to_f16_k(const float* __restrict__ in, half_t* __restrict__ out, int n4) {
  const int i = blockIdx.x * 256 + threadIdx.x;
  if (i < n4) {
    const float4 f = reinterpret_cast<const float4*>(in)[i];
    half4v h; h[0] = (half_t)f.x; h[1] = (half_t)f.y; h[2] = (half_t)f.z; h[3] = (half_t)f.w;
    reinterpret_cast<half4v*>(out)[i] = h;
  }
}

// ------------------------------------------------------------- workspace map
constexpr size_t OFF_XH   = 0;                                   // [B*T,C] f16
constexpr size_t OFF_YH   = OFF_XH   + (size_t)Bc*Tc*Cc*2;
constexpr size_t OFF_WQ   = OFF_YH   + (size_t)Bc*Mc*Cc*2;
constexpr size_t OFF_WP   = OFF_WQ   + (size_t)3*Cc*Cc*2;
constexpr size_t OFF_QX   = OFF_WP   + (size_t)Cc*Cc*2;          // [z,T,D] scaled
constexpr size_t OFF_KX   = OFF_QX   + (size_t)Bc*Hc*Tc*Dc*2;    // [z,T,D]
constexpr size_t OFF_VXT  = OFF_KX   + (size_t)Bc*Hc*Tc*Dc*2;    // [z,D,T]
constexpr size_t OFF_QYT  = OFF_VXT  + (size_t)Bc*Hc*Tc*Dc*2;    // [z,D,M] scaled
constexpr size_t OFF_KY   = OFF_QYT  + (size_t)Bc*Hc*Mc*Dc*2;    // [z,M,D]
constexpr size_t OFF_KYT  = OFF_KY   + (size_t)Bc*Hc*Mc*Dc*2;    // [z,D,M]
constexpr size_t OFF_VYT  = OFF_KYT  + (size_t)Bc*Hc*Mc*Dc*2;    // [z,D,M]
constexpr size_t OFF_WT   = OFF_VYT  + (size_t)Bc*Hc*Mc*Dc*2;    // [z,64,64]
constexpr size_t OFF_Q2   = OFF_WT   + (size_t)Bc*Hc*Dc*Dc*2;    // [z,T,D]
constexpr size_t OFF_CV2  = OFF_Q2   + (size_t)Bc*Hc*Tc*Dc*2;    // [B,T,C]
constexpr size_t OFF_DH   = OFF_CV2  + (size_t)Bc*Tc*Cc*2;       // [B,T,C]
constexpr size_t OFF_MPK  = OFF_DH   + (size_t)Bc*Tc*Cc*2;       // [T,16,16] u8
// total ~45 MB

extern "C" void kernel_launch(void* const* d_in, const int* in_sizes, int n_in,
                              void* d_out, int out_size, void* d_ws, size_t ws_size,
                              hipStream_t stream) {
  const float* x      = (const float*)d_in[0];
  const float* y      = (const float*)d_in[1];
  const int*   mask   = (const int*)  d_in[2];
  const float* qkv_b  = (const float*)d_in[4];
  const float* proj_b = (const float*)d_in[6];
  float* out = (float*)d_out;
  char* ws = (char*)d_ws;

  half_t* XH   = (half_t*)(ws + OFF_XH);
  half_t* YH   = (half_t*)(ws + OFF_YH);
  half_t* WQ   = (half_t*)(ws + OFF_WQ);
  half_t* WP   = (half_t*)(ws + OFF_WP);
  half_t* QX   = (half_t*)(ws + OFF_QX);
  half_t* KX   = (half_t*)(ws + OFF_KX);
  half_t* VXT  = (half_t*)(ws + OFF_VXT);
  half_t* QYT  = (half_t*)(ws + OFF_QYT);
  half_t* KY   = (half_t*)(ws + OFF_KY);
  half_t* KYT  = (half_t*)(ws + OFF_KYT);
  half_t* VYT  = (half_t*)(ws + OFF_VYT);
  half_t* WT   = (half_t*)(ws + OFF_WT);
  half_t* Q2   = (half_t*)(ws + OFF_Q2);
  half_t* CV2  = (half_t*)(ws + OFF_CV2);
  half_t* DH   = (half_t*)(ws + OFF_DH);
  unsigned char* MPK = (unsigned char*)(ws + OFF_MPK);

  // fp32 -> f16 converts + mask packing
  f32_to_f16_k<<<(Bc*Tc*Cc/4 + 255) / 256, 256, 0, stream>>>(x, XH, Bc*Tc*Cc/4);
  f32_to_f16_k<<<(Bc*Mc*Cc/4 + 255) / 256, 256, 0, stream>>>(y, YH, Bc*Mc*Cc/4);
  f32_to_f16_k<<<(3*Cc*Cc/4 + 255) / 256, 256, 0, stream>>>((const float*)d_in[3], WQ, 3*Cc*Cc/4);
  f32_to_f16_k<<<(Cc*Cc/4 + 255) / 256, 256, 0, stream>>>((const float*)d_in[5], WP, Cc*Cc/4);
  pack_mask<<<Tc * 256 / 256, 256, 0, stream>>>(mask, MPK);

  // qkv projections
  {
    EpiParams ep{}; ep.h0 = QX; ep.h1 = KX; ep.h2 = VXT; ep.bias = qkv_b; ep.seq = Tc;
    gemm_nt<128,128,2,2,EPI_QKV_X><<<dim3(12, 32, 1), 256, 0, stream>>>(
        XH, WQ, Cc, Cc, Cc, 0, 0, ep);
  }
  {
    EpiParams ep{}; ep.h0 = QYT; ep.h1 = KY; ep.h2 = VYT; ep.h3 = KYT;
    ep.bias = qkv_b; ep.seq = Mc;
    gemm_nt<64,128,2,2,EPI_QKV_Y><<<dim3(12, 32, 1), 256, 0, stream>>>(
        YH, WQ, Cc, Cc, Cc, 0, 0, ep);
  }

  // WT[z][d2][d1] = 0.125 * sum_m QYTs[d2,m] KYT[d1,m]  (total scale^3)
  {
    EpiParams ep{}; ep.h0 = WT; ep.scale = 0.125f; ep.ldc = 64; ep.bstride = 64 * 64;
    gemm_nt<64,64,2,2,EPI_F16STORE><<<dim3(1, 1, Bc*Hc), 256, 0, stream>>>(
        QYT, KYT, Mc, Mc, Mc, (long)Dc*Mc, (long)Dc*Mc, ep);
  }
  // Q2[z][t][d2] = sum_d1 QXs[t,d1] WT[d2,d1]
  {
    EpiParams ep{}; ep.h0 = Q2; ep.scale = 1.f; ep.ldc = 64; ep.bstride = (long)Tc * 64;
    gemm_nt<128,64,2,2,EPI_F16STORE><<<dim3(1, Tc/128, Bc*Hc), 256, 0, stream>>>(
        QX, WT, Dc, Dc, Dc, (long)Tc*Dc, (long)64*64, ep);
  }

  // chained attention (masked): softmax(Q2 Kx^T) Vx -> CV2
  flash_attn<0, true><<<dim3((Tc/64) * Bc*Hc), 256, 0, stream>>>(
      Q2, KX, VXT, MPK, CV2, nullptr, Tc);
  // first attention: softmax(QXs Ky^T) Vy - CV2 -> DH
  flash_attn<1, false><<<dim3((Tc/64) * Bc*Hc), 256, 0, stream>>>(
      QX, KY, VYT, nullptr, DH, CV2, Mc);

  // out = DH @ proj_w^T + proj_b
  {
    EpiParams ep{}; ep.f0 = out; ep.bias = proj_b;
    gemm_nt<128,64,2,2,EPI_PROJ><<<dim3(8, 32, 1), 256, 0, stream>>>(
        DH, WP, Cc, Cc, Cc, 0, 0, ep);
  }
}